// Round 20
// baseline (169.613 us; speedup 1.0000x reference)
//
#include <hip/hip_runtime.h>

typedef __bf16 bf16x8 __attribute__((ext_vector_type(8)));
typedef float f32x4 __attribute__((ext_vector_type(4)));

// mask position tables
__constant__ int SL_I[3][9] = {{1,1,1,2,2,2,3,3,3},{0,0,2,4,4,0,0,0,0},{0,0,1,1,2,3,3,4,4}};
__constant__ int SL_J[3][9] = {{1,2,3,1,2,3,1,2,3},{0,4,2,0,4,0,0,0,0},{1,3,0,4,2,0,4,1,3}};
__constant__ int SL_S[3][9] = {{6,7,8,11,12,13,16,17,18},{0,4,12,20,24,0,0,0,0},{1,3,5,9,12,15,19,21,23}};

#define GLDS16(gsrc, ldst)                                                        \
  __builtin_amdgcn_global_load_lds(                                               \
      (const __attribute__((address_space(1))) unsigned int*)(gsrc),              \
      (__attribute__((address_space(3))) unsigned int*)(ldst), 16, 0, 0)

#define SBAR()  asm volatile("s_barrier" ::: "memory")
#define VMW(n)  asm volatile("s_waitcnt vmcnt(" #n ")" ::: "memory")
#define SCB()   __builtin_amdgcn_sched_barrier(0)

static __device__ __forceinline__ unsigned short f2b(float f) {
  return __builtin_bit_cast(unsigned short, (__bf16)f);
}
static __device__ __forceinline__ float b2f(unsigned short u) {
  unsigned int b = ((unsigned int)u) << 16;
  return __builtin_bit_cast(float, b);
}
// mish(x) = x*w/(w+2), w = u*(u+2), u = e^x
static __device__ __forceinline__ float mish_f(float x) {
  float u = __expf(x);
  float w = u * (u + 2.0f);
  float r = x * w * __builtin_amdgcn_rcpf(w + 2.0f);
  return (x > 20.0f) ? x : r;
}
// A-side swizzle within a 64-col chunk (involution)
static __device__ __forceinline__ int swoff(int c, int r) {
  return (c & ~63) | ((c & 63) ^ ((r & 7) << 3));
}

// ---- prep_x: X [4096][64][49] -> Xb fragment-major [49][mt32][oc8][m128][k8] bf16 ----
// block = (s-chunk of 7, b-chunk of 64). LDS tile [7][64][72pad]. Stores are
// lane-contiguous: wave writes 1 KB contiguous (lane=m, 16 B each) -> 4 reqs/KB not 64.
__global__ __launch_bounds__(512) void prep_x_k(const float* __restrict__ X,
                                                unsigned short* __restrict__ Xb) {
  __shared__ unsigned short tile[7 * 64 * 72];   // 64,512 B
  const int t = threadIdx.x;
  const int s0 = blockIdx.x * 7;       // 7 s-chunks
  const int bchunk = blockIdx.y;       // 64 b-chunks
  const int b0 = bchunk * 64;
  // load: X[b0+i][c][s0..s0+7) -> tile[j][i][c]  (7 consecutive floats -> L1-backed)
  for (int ic = t; ic < 4096; ic += 512) {
    const int i = ic >> 6, c = ic & 63;
    const float* src = X + ((size_t)(b0 + i) * 64 + c) * 49 + s0;
    unsigned short* dst = tile + i * 72 + c;
#pragma unroll
    for (int j = 0; j < 7; ++j)
      dst[j * 4608] = f2b(src[j]);
  }
  __syncthreads();
  // store: wave w handles (s_local, oc) pairs; lane m -> one uint4; 1 KB contiguous/instr
  const int m = t & 63, w = t >> 6;
  const int mt = bchunk >> 1, mof = (bchunk & 1) * 64;
#pragma unroll
  for (int it = 0; it < 7; ++it) {
    const int pair = it * 8 + w;       // 56 pairs = 7 s x 8 oc
    const int sl = pair >> 3, oc = pair & 7;
    uint4 v = *(const uint4*)(tile + (sl * 64 + m) * 72 + oc * 8);
    *(uint4*)(Xb + ((size_t)(((s0 + sl) * 32 + mt) * 8 + oc)) * 1024 + (mof + m) * 8) = v;
  }
}

// ---- prep_rest: [0,1728) w5 (LDS-staged) | [1728,2592) w12 | [2592,2619) bn ----
__global__ __launch_bounds__(256) void prep_rest_k(const float* __restrict__ W5,
                                                   const float* __restrict__ W1, const float* __restrict__ W2,
                                                   const float* __restrict__ b5, const float* __restrict__ gamma,
                                                   const float* __restrict__ beta, const float* __restrict__ rmean,
                                                   const float* __restrict__ rvar,
                                                   unsigned short* __restrict__ W5c,
                                                   unsigned short* __restrict__ W1c, unsigned short* __restrict__ W2c,
                                                   float* __restrict__ bn_a, float* __restrict__ bn_c) {
  __shared__ float rows[6400];   // 25,600 B (w5 branch only)
  const int bid = blockIdx.x;
  const int t = threadIdx.x;
  if (bid < 1728) {
    // ---- prep_w5 (LDS-staged): block = (gp, nt, 4-row chunk) ----
    const int chunk = bid & 31;
    const int nt = (bid >> 5) & 1;
    const int gp = bid >> 6;
    const int g = gp / 9;
    const int nm = (g == 1) ? 5 : 9;
    const int n0 = chunk * 4;
    const float* src = W5 + ((size_t)(gp * 256 + nt * 128 + n0)) * 1600;
    for (int i = t; i < 6400; i += 256) rows[i] = src[i];
    __syncthreads();
    for (int i = t; i < 576; i += 256) {   // u(9) x q(8) x k4(2) x n(4)
      const int n  = i & 3;
      const int k4 = (i >> 2) & 1;
      const int q  = (i >> 3) & 7;
      const int u  = i >> 6;
      if (u >= nm) continue;
      const int s = SL_S[g][u];
      const float* rp = rows + n * 1600 + s;
      const int c0 = q * 8 + k4 * 4;
      ushort4 v = {f2b(rp[(c0 + 0) * 25]), f2b(rp[(c0 + 1) * 25]),
                   f2b(rp[(c0 + 2) * 25]), f2b(rp[(c0 + 3) * 25])};
      *(ushort4*)(W5c + ((size_t)((gp * 9 + u) * 2 + nt)) * 8192 + q * 1024 + (n0 + n) * 8 + k4 * 4) = v;
    }
  } else if (bid < 1728 + 864) {
    // ---- prep_w12: W1/W2 -> fragment-major [gp][kt8][q4][n256][k8] ----
    int tid = (bid - 1728) * 256 + t;   // 221,184
    if (tid >= 221184) return;
    int n  = tid & 255;
    int q  = (tid >> 8) & 3;
    int kt = (tid >> 10) & 7;
    int gp = tid >> 13;
    size_t src = (size_t)(gp * 256 + n) * 256 + kt * 32 + q * 8;
    float4 a0 = *(const float4*)(W1 + src);
    float4 a1 = *(const float4*)(W1 + src + 4);
    float4 b0 = *(const float4*)(W2 + src);
    float4 b1 = *(const float4*)(W2 + src + 4);
    ushort4 ua0 = {f2b(a0.x), f2b(a0.y), f2b(a0.z), f2b(a0.w)};
    ushort4 ua1 = {f2b(a1.x), f2b(a1.y), f2b(a1.z), f2b(a1.w)};
    ushort4 ub0 = {f2b(b0.x), f2b(b0.y), f2b(b0.z), f2b(b0.w)};
    ushort4 ub1 = {f2b(b1.x), f2b(b1.y), f2b(b1.z), f2b(b1.w)};
    *(ushort4*)(W1c + (size_t)tid * 8) = ua0;
    *(ushort4*)(W1c + (size_t)tid * 8 + 4) = ua1;
    *(ushort4*)(W2c + (size_t)tid * 8) = ub0;
    *(ushort4*)(W2c + (size_t)tid * 8 + 4) = ub1;
  } else {
    // ---- prep_bn ----
    int i = (bid - 1728 - 864) * 256 + t;
    if (i < 27 * 256) {
      float a = gamma[i] * rsqrtf(rvar[i] + 1e-5f);
      bn_a[i] = a;
      bn_c[i] = (b5[i] - rmean[i]) * a + beta[i];
    }
  }
}

// ---- stage 1: z = Xb x W5c^T, BN + mish -> H bf16 (R16-proven 3-buffer pipeline) ----
__global__ __launch_bounds__(512) void gemm1_k(const unsigned short* __restrict__ Xb,
                                               const unsigned short* __restrict__ W5c,
                                               const float* __restrict__ bn_a, const float* __restrict__ bn_c,
                                               unsigned short* __restrict__ H) {
  __shared__ unsigned short smem[24576];   // 3 x (dA 4096 + dB 4096 shorts) = 48 KB
  const int t = threadIdx.x;
  const int lane = t & 63;
  const int w = t >> 6;
  const int wm = w >> 2, wn = w & 3;
  const int l15 = lane & 15, l4 = lane >> 4;
  const int mt = blockIdx.x;
  const int m0 = mt * 128;
  const int nt = blockIdx.y;
  const int n0 = nt * 128;
  const int gp = blockIdx.z;
  const int g = gp / 9, p = gp - g * 9;
  const int pk = p / 3, pv = p - pk * 3;
  const int nm = (g == 1) ? 5 : 9;
  const int S = 2 * nm;

  const f32x4 zero = {0.f, 0.f, 0.f, 0.f};
  f32x4 acc[4][2];
#pragma unroll
  for (int i = 0; i < 4; ++i)
#pragma unroll
    for (int j = 0; j < 2; ++j) acc[i][j] = zero;

  auto STAGE = [&](int pbuf, int st) {
    const int u = st >> 1, kh = st & 1;
    const int s = (pk + SL_I[g][u]) * 7 + (pv + SL_J[g][u]);
    const unsigned short* srcA = Xb + ((size_t)((s * 32 + mt) * 2 + kh)) * 4096;
    const unsigned short* srcB = W5c + ((size_t)((gp * 9 + u) * 2 + nt)) * 8192 + kh * 4096;
    unsigned short* dA = smem + pbuf * 8192;
    unsigned short* dB = dA + 4096;
    GLDS16(srcA + t * 8, dA + t * 8);
    GLDS16(srcB + t * 8, dB + t * 8);
  };

  STAGE(0, 0);
  for (int st = 0; st < S; ++st) {
    if (st + 1 < S) { STAGE((st + 1) % 3, st + 1); VMW(2); } else { VMW(0); }
    SBAR(); SCB();
    const unsigned short* lA = smem + (st % 3) * 8192;
    const unsigned short* lB = lA + 4096;
    bf16x8 af[4], bfr[2];
#pragma unroll
    for (int f4 = 0; f4 < 4; ++f4)
      af[f4] = *reinterpret_cast<const bf16x8*>(lA + l4 * 1024 + (wm * 64 + f4 * 16 + l15) * 8);
#pragma unroll
    for (int f2 = 0; f2 < 2; ++f2)
      bfr[f2] = *reinterpret_cast<const bf16x8*>(lB + l4 * 1024 + (wn * 32 + f2 * 16 + l15) * 8);
#pragma unroll
    for (int i = 0; i < 4; ++i)
#pragma unroll
      for (int j = 0; j < 2; ++j)
        acc[i][j] = __builtin_amdgcn_mfma_f32_16x16x32_bf16(af[i], bfr[j], acc[i][j], 0, 0, 0);
  }
  __syncthreads();
  // epilogue: BN + mish -> bf16, LDS transpose -> dwordx4 stores (H pre-swizzled)
#pragma unroll
  for (int j = 0; j < 2; ++j) {
    const int col = wn * 32 + j * 16 + l15;
    const float a  = bn_a[gp * 256 + n0 + col];
    const float cc = bn_c[gp * 256 + n0 + col];
#pragma unroll
    for (int i = 0; i < 4; ++i) {
      const int r0 = wm * 64 + i * 16 + l4 * 4;
#pragma unroll
      for (int e = 0; e < 4; ++e) {
        const int r = r0 + e;
        float z = acc[i][j][e] * a + cc;
        smem[r * 128 + (col ^ ((r & 7) << 3))] = f2b(mish_f(z));
      }
    }
  }
  __syncthreads();
  {
    unsigned short* Hg = H + (size_t)gp * 1048576;
#pragma unroll
    for (int it = 0; it < 4; ++it) {
      int idx = it * 512 + t;
      int row = idx >> 4, seg = idx & 15;
      int c8 = (seg * 8) ^ ((row & 7) << 3);
      uint4 v = *(const uint4*)(smem + row * 128 + c8);
      int colout = n0 + (seg >> 3) * 64 + (((seg & 7) ^ (row & 7)) << 3);
      *(uint4*)(Hg + (size_t)(m0 + row) * 256 + colout) = v;
    }
  }
}

// ---- fused stages 2+3 with counted-vmcnt 3-buffer pipeline (R14/R16-proven) ----
__global__ __launch_bounds__(512) void gemm23f_k(const unsigned short* __restrict__ Hb,
                                                 const unsigned short* __restrict__ W1c,
                                                 const unsigned short* __restrict__ W2c,
                                                 const float* __restrict__ b1, const float* __restrict__ b2,
                                                 unsigned short* __restrict__ Obuf) {
  extern __shared__ unsigned short smem[];
  unsigned short* stB = smem;
  unsigned short* stA = smem + 24576;
  unsigned short* h1  = smem + 24576;
  const int t = threadIdx.x;
  const int lane = t & 63;
  const int w = t >> 6;
  const int wm = w >> 2, wn = w & 3;
  const int l15 = lane & 15, l4 = lane >> 4;
  const int sw = l15 & 7;
  const int m0 = blockIdx.x * 64;
  const int gp = blockIdx.y;

  const f32x4 zero = {0.f, 0.f, 0.f, 0.f};
  f32x4 acc[2][4];
#pragma unroll
  for (int i = 0; i < 2; ++i)
#pragma unroll
    for (int j = 0; j < 4; ++j) acc[i][j] = zero;

  auto STAGE_A = [&](int pbuf, int kt64) {
    unsigned short* dA = stA + pbuf * 4096;
    GLDS16(Hb + (size_t)(gp * 4096 + m0 + (t >> 3)) * 256 + kt64 * 64 + (t & 7) * 8, dA + t * 8);
  };
  auto STAGE_B = [&](const unsigned short* Wc, int kt32, int pbuf) {
    unsigned short* dB = stB + pbuf * 8192;
    const unsigned short* src = Wc + ((size_t)(gp * 8 + kt32)) * 8192;
#pragma unroll
    for (int it = 0; it < 2; ++it) {
      int idx = it * 512 + t;
      GLDS16(src + idx * 8, dB + idx * 8);
    }
  };

  // ---- phase 1: h1 = mish(H x W1^T + b1), 8 steps of BK=32 ----
  STAGE_A(0, 0);
  STAGE_B(W1c, 0, 0);
#pragma unroll
  for (int kt = 0; kt < 8; ++kt) {
    if (kt < 7) STAGE_B(W1c, kt + 1, (kt + 1) % 3);
    if ((kt & 1) == 0 && kt < 6) STAGE_A((kt / 2 + 1) % 3, kt / 2 + 1);
    if (kt < 6) { VMW(3); } else if (kt == 6) { VMW(2); } else { VMW(0); }
    SBAR(); SCB();
    const unsigned short* lA = stA + ((kt >> 1) % 3) * 4096;
    const unsigned short* lB = stB + (kt % 3) * 8192;
    bf16x8 af[2], bfr[4];
#pragma unroll
    for (int f2 = 0; f2 < 2; ++f2)
      af[f2] = *reinterpret_cast<const bf16x8*>(lA + (wm * 32 + f2 * 16 + l15) * 64 + ((((kt & 1) * 4 + l4) ^ sw) << 3));
#pragma unroll
    for (int f4 = 0; f4 < 4; ++f4)
      bfr[f4] = *reinterpret_cast<const bf16x8*>(lB + l4 * 2048 + (wn * 64 + f4 * 16 + l15) * 8);
#pragma unroll
    for (int i = 0; i < 2; ++i)
#pragma unroll
      for (int j = 0; j < 4; ++j)
        acc[i][j] = __builtin_amdgcn_mfma_f32_16x16x32_bf16(af[i], bfr[j], acc[i][j], 0, 0, 0);
  }
  __syncthreads();
  STAGE_B(W2c, 0, 0);              // prefetch W2 step 0 under the h1 epilogue
#pragma unroll
  for (int j = 0; j < 4; ++j) {
    const int c = wn * 64 + j * 16 + l15;
    const float bi = b1[gp * 256 + c];
#pragma unroll
    for (int i = 0; i < 2; ++i) {
      const int r0 = wm * 32 + i * 16 + l4 * 4;
#pragma unroll
      for (int e = 0; e < 4; ++e) {
        const int r = r0 + e;
        h1[r * 256 + swoff(c, r)] = f2b(mish_f(acc[i][j][e] + bi));
      }
    }
  }
  __syncthreads();                 // publishes h1; drains W2 step-0 stage

  // ---- phase 2: o = h1 x W2^T + b2, 8 steps of BK=32, staged 3-buffer ----
#pragma unroll
  for (int i = 0; i < 2; ++i)
#pragma unroll
    for (int j = 0; j < 4; ++j) acc[i][j] = zero;
#pragma unroll
  for (int kt = 0; kt < 8; ++kt) {
    if (kt < 7) STAGE_B(W2c, kt + 1, (kt + 1) % 3);
    if (kt < 7) { VMW(2); } else { VMW(0); }
    SBAR(); SCB();
    const unsigned short* lB = stB + (kt % 3) * 8192;
    bf16x8 af[2], bfr[4];
#pragma unroll
    for (int f2 = 0; f2 < 2; ++f2) {
      const int row = wm * 32 + f2 * 16 + l15;
      af[f2] = *reinterpret_cast<const bf16x8*>(
          h1 + row * 256 + (kt >> 1) * 64 + ((((kt & 1) * 4 + l4) ^ sw) << 3));
    }
#pragma unroll
    for (int f4 = 0; f4 < 4; ++f4)
      bfr[f4] = *reinterpret_cast<const bf16x8*>(lB + l4 * 2048 + (wn * 64 + f4 * 16 + l15) * 8);
#pragma unroll
    for (int i = 0; i < 2; ++i)
#pragma unroll
      for (int j = 0; j < 4; ++j)
        acc[i][j] = __builtin_amdgcn_mfma_f32_16x16x32_bf16(af[i], bfr[j], acc[i][j], 0, 0, 0);
  }
  __syncthreads();
  unsigned short* tr = stB;
#pragma unroll
  for (int j = 0; j < 4; ++j) {
    const int c = wn * 64 + j * 16 + l15;
    const float bi = b2[gp * 256 + c];
#pragma unroll
    for (int i = 0; i < 2; ++i) {
      const int r0 = wm * 32 + i * 16 + l4 * 4;
#pragma unroll
      for (int e = 0; e < 4; ++e) {
        const int r = r0 + e;
        tr[r * 256 + swoff(c, r)] = f2b(acc[i][j][e] + bi);
      }
    }
  }
  __syncthreads();
  {
    unsigned short* Og = Obuf + (size_t)gp * 1048576;
#pragma unroll
    for (int it = 0; it < 4; ++it) {
      int idx = it * 512 + t;
      int row = idx >> 5, seg = idx & 31;
      int c8 = swoff(seg * 8, row);
      uint4 v = *(const uint4*)(tr + row * 256 + c8);
      *(uint4*)(Og + (size_t)(m0 + row) * 256 + seg * 8) = v;
    }
  }
}

// ---- final: copy = sum_{gp<9} o, jump = sum_{gp>=9} o, out = copy*jump ----
__global__ __launch_bounds__(256) void final_k(const unsigned short* __restrict__ O, float* __restrict__ out) {
  const size_t base = ((size_t)blockIdx.x * 256 + threadIdx.x) * 8;
  float cs[8], js[8];
#pragma unroll
  for (int e = 0; e < 8; ++e) { cs[e] = 0.f; js[e] = 0.f; }
#pragma unroll
  for (int gp = 0; gp < 27; ++gp) {
    uint4 v = *(const uint4*)(O + (size_t)gp * 1048576 + base);
    const unsigned short* pv = (const unsigned short*)&v;
    if (gp < 9) {
#pragma unroll
      for (int e = 0; e < 8; ++e) cs[e] += b2f(pv[e]);
    } else {
#pragma unroll
      for (int e = 0; e < 8; ++e) js[e] += b2f(pv[e]);
    }
  }
  float4 o0 = {cs[0] * js[0], cs[1] * js[1], cs[2] * js[2], cs[3] * js[3]};
  float4 o1 = {cs[4] * js[4], cs[5] * js[5], cs[6] * js[6], cs[7] * js[7]};
  *(float4*)(out + base) = o0;
  *(float4*)(out + base + 4) = o1;
}

extern "C" void kernel_launch(void* const* d_in, const int* in_sizes, int n_in,
                              void* d_out, int out_size, void* d_ws, size_t ws_size,
                              hipStream_t stream) {
  const float* X     = (const float*)d_in[0];
  const float* W5    = (const float*)d_in[1];
  const float* b5    = (const float*)d_in[2];
  const float* gamma = (const float*)d_in[3];
  const float* beta  = (const float*)d_in[4];
  const float* rmean = (const float*)d_in[5];
  const float* rvar  = (const float*)d_in[6];
  const float* W1    = (const float*)d_in[7];
  const float* b1    = (const float*)d_in[8];
  const float* W2    = (const float*)d_in[9];
  const float* b2    = (const float*)d_in[10];
  float* out = (float*)d_out;
  char* ws = (char*)d_ws;

  unsigned short* W5c  = (unsigned short*)(ws);              //  7,962,624
  unsigned short* W1c  = (unsigned short*)(ws + 7962624);    //  3,538,944
  unsigned short* W2c  = (unsigned short*)(ws + 11501568);   //  3,538,944
  float*          bn_a = (float*)(ws + 15040512);            //     27,648
  float*          bn_c = (float*)(ws + 15068160);            //     27,648
  unsigned short* Xb   = (unsigned short*)(ws + 15095808);   // 25,690,112
  unsigned short* Hbuf = (unsigned short*)(ws + 40785920);   // 56,623,104
  unsigned short* Obuf = (unsigned short*)(ws + 97409024);   // 56,623,104

  (void)hipFuncSetAttribute(reinterpret_cast<const void*>(gemm23f_k),
                            hipFuncAttributeMaxDynamicSharedMemorySize, 81920);

  prep_x_k<<<dim3(7, 64), 512, 0, stream>>>(X, Xb);
  prep_rest_k<<<2619, 256, 0, stream>>>(W5, W1, W2, b5, gamma, beta, rmean, rvar,
                                        W5c, W1c, W2c, bn_a, bn_c);

  gemm1_k<<<dim3(32, 2, 27), 512, 0, stream>>>(Xb, W5c, bn_a, bn_c, Hbuf);
  gemm23f_k<<<dim3(64, 27), 512, 81920, stream>>>(Hbuf, W1c, W2c, b1, b2, Obuf);
  final_k<<<512, 256, 0, stream>>>(Obuf, out);
}

// Round 21
// 163.674 us; speedup vs baseline: 1.0363x; 1.0363x over previous
//
#include <hip/hip_runtime.h>

typedef __bf16 bf16x8 __attribute__((ext_vector_type(8)));
typedef float f32x4 __attribute__((ext_vector_type(4)));

// mask position tables
__constant__ int SL_I[3][9] = {{1,1,1,2,2,2,3,3,3},{0,0,2,4,4,0,0,0,0},{0,0,1,1,2,3,3,4,4}};
__constant__ int SL_J[3][9] = {{1,2,3,1,2,3,1,2,3},{0,4,2,0,4,0,0,0,0},{1,3,0,4,2,0,4,1,3}};
__constant__ int SL_S[3][9] = {{6,7,8,11,12,13,16,17,18},{0,4,12,20,24,0,0,0,0},{1,3,5,9,12,15,19,21,23}};

#define GLDS16(gsrc, ldst)                                                        \
  __builtin_amdgcn_global_load_lds(                                               \
      (const __attribute__((address_space(1))) unsigned int*)(gsrc),              \
      (__attribute__((address_space(3))) unsigned int*)(ldst), 16, 0, 0)

#define SBAR()  asm volatile("s_barrier" ::: "memory")
#define VMW(n)  asm volatile("s_waitcnt vmcnt(" #n ")" ::: "memory")
#define SCB()   __builtin_amdgcn_sched_barrier(0)

static __device__ __forceinline__ unsigned short f2b(float f) {
  return __builtin_bit_cast(unsigned short, (__bf16)f);
}
static __device__ __forceinline__ float b2f(unsigned short u) {
  unsigned int b = ((unsigned int)u) << 16;
  return __builtin_bit_cast(float, b);
}
// mish(x) = x*w/(w+2), w = u*(u+2), u = e^x
static __device__ __forceinline__ float mish_f(float x) {
  float u = __expf(x);
  float w = u * (u + 2.0f);
  float r = x * w * __builtin_amdgcn_rcpf(w + 2.0f);
  return (x > 20.0f) ? x : r;
}
// A-side swizzle within a 64-col chunk (involution)
static __device__ __forceinline__ int swoff(int c, int r) {
  return (c & ~63) | ((c & 63) ^ ((r & 7) << 3));
}

// ---- merged prep: [0,512) x | [512,2240) w5 (LDS-staged) | [2240,3104) w12 | [3104,3131) bn ----
__global__ __launch_bounds__(256) void prep_all_k(const float* __restrict__ X,
                                                  const float* __restrict__ W5,
                                                  const float* __restrict__ W1, const float* __restrict__ W2,
                                                  const float* __restrict__ b5, const float* __restrict__ gamma,
                                                  const float* __restrict__ beta, const float* __restrict__ rmean,
                                                  const float* __restrict__ rvar,
                                                  unsigned short* __restrict__ Xb,
                                                  unsigned short* __restrict__ W5c,
                                                  unsigned short* __restrict__ W1c, unsigned short* __restrict__ W2c,
                                                  float* __restrict__ bn_a, float* __restrict__ bn_c) {
  __shared__ char shmem[50304];   // max(8*3144*2, 6400*4); ~3 blocks/CU
  const int bid = blockIdx.x;
  const int t = threadIdx.x;
  if (bid < 512) {
    // ---- prep_x: X -> Xb fragment-major [49][mt32][oc8][m128][k8]; 8 b-rows/block ----
    // loads coalesced row-by-row; stores lane-grouped: lanes 0-7 = 8 consecutive m
    // for one (s,oc) -> 128 B fully-covered per group, 16 full lines per instruction.
    unsigned short* tile16 = (unsigned short*)shmem;   // [8][3144 pad]
    const int b0 = bid * 8;
    const float* xp = X + (size_t)b0 * 3136;
#pragma unroll
    for (int r = 0; r < 8; ++r)
      for (int i = t; i < 3136; i += 256)
        tile16[r * 3144 + i] = f2b(xp[r * 3136 + i]);
    __syncthreads();
    const int mt = b0 >> 7;
    const int mr = (b0 & 127) + (t & 7);
    const unsigned short* tr_ = tile16 + (t & 7) * 3144;
    for (int p = (t >> 3); p < 392; p += 32) {   // 49 s x 8 oc
      const int s = p >> 3, oc = p & 7, c = oc * 8;
      unsigned int vv[4];
#pragma unroll
      for (int k = 0; k < 4; ++k) {
        unsigned int lo = tr_[(c + 2 * k) * 49 + s];
        unsigned int hi = tr_[(c + 2 * k + 1) * 49 + s];
        vv[k] = lo | (hi << 16);
      }
      *(uint4*)(Xb + ((size_t)((s * 32 + mt) * 8 + oc)) * 1024 + mr * 8) =
          make_uint4(vv[0], vv[1], vv[2], vv[3]);
    }
  } else if (bid < 512 + 1728) {
    // ---- prep_w5 (LDS-staged): block = (gp, nt, 4-row chunk) ----
    float* rows = (float*)shmem;           // 4 x 1600 f32 = 25600 B
    const int id = bid - 512;
    const int chunk = id & 31;
    const int nt = (id >> 5) & 1;
    const int gp = id >> 6;
    const int g = gp / 9;
    const int nm = (g == 1) ? 5 : 9;
    const int n0 = chunk * 4;
    const float* src = W5 + ((size_t)(gp * 256 + nt * 128 + n0)) * 1600;
    for (int i = t; i < 6400; i += 256) rows[i] = src[i];
    __syncthreads();
    for (int i = t; i < 576; i += 256) {   // u(9) x q(8) x k4(2) x n(4)
      const int n  = i & 3;
      const int k4 = (i >> 2) & 1;
      const int q  = (i >> 3) & 7;
      const int u  = i >> 6;
      if (u >= nm) continue;
      const int s = SL_S[g][u];
      const float* rp = rows + n * 1600 + s;
      const int c0 = q * 8 + k4 * 4;
      ushort4 v = {f2b(rp[(c0 + 0) * 25]), f2b(rp[(c0 + 1) * 25]),
                   f2b(rp[(c0 + 2) * 25]), f2b(rp[(c0 + 3) * 25])};
      *(ushort4*)(W5c + ((size_t)((gp * 9 + u) * 2 + nt)) * 8192 + q * 1024 + (n0 + n) * 8 + k4 * 4) = v;
    }
  } else if (bid < 512 + 1728 + 864) {
    // ---- prep_w12: W1/W2 -> fragment-major [gp][kt8][q4][n256][k8] ----
    int tid = (bid - 512 - 1728) * 256 + t;   // 221,184
    if (tid >= 221184) return;
    int n  = tid & 255;
    int q  = (tid >> 8) & 3;
    int kt = (tid >> 10) & 7;
    int gp = tid >> 13;
    size_t src = (size_t)(gp * 256 + n) * 256 + kt * 32 + q * 8;
    float4 a0 = *(const float4*)(W1 + src);
    float4 a1 = *(const float4*)(W1 + src + 4);
    float4 b0 = *(const float4*)(W2 + src);
    float4 b1 = *(const float4*)(W2 + src + 4);
    ushort4 ua0 = {f2b(a0.x), f2b(a0.y), f2b(a0.z), f2b(a0.w)};
    ushort4 ua1 = {f2b(a1.x), f2b(a1.y), f2b(a1.z), f2b(a1.w)};
    ushort4 ub0 = {f2b(b0.x), f2b(b0.y), f2b(b0.z), f2b(b0.w)};
    ushort4 ub1 = {f2b(b1.x), f2b(b1.y), f2b(b1.z), f2b(b1.w)};
    *(ushort4*)(W1c + (size_t)tid * 8) = ua0;
    *(ushort4*)(W1c + (size_t)tid * 8 + 4) = ua1;
    *(ushort4*)(W2c + (size_t)tid * 8) = ub0;
    *(ushort4*)(W2c + (size_t)tid * 8 + 4) = ub1;
  } else {
    // ---- prep_bn ----
    int i = (bid - 512 - 1728 - 864) * 256 + t;
    if (i < 27 * 256) {
      float a = gamma[i] * rsqrtf(rvar[i] + 1e-5f);
      bn_a[i] = a;
      bn_c[i] = (b5[i] - rmean[i]) * a + beta[i];
    }
  }
}

// ---- stage 1: z = Xb x W5c^T, BN + mish -> H bf16 (R16-proven 3-buffer pipeline) ----
__global__ __launch_bounds__(512) void gemm1_k(const unsigned short* __restrict__ Xb,
                                               const unsigned short* __restrict__ W5c,
                                               const float* __restrict__ bn_a, const float* __restrict__ bn_c,
                                               unsigned short* __restrict__ H) {
  __shared__ unsigned short smem[24576];   // 3 x (dA 4096 + dB 4096 shorts) = 48 KB
  const int t = threadIdx.x;
  const int lane = t & 63;
  const int w = t >> 6;
  const int wm = w >> 2, wn = w & 3;
  const int l15 = lane & 15, l4 = lane >> 4;
  const int mt = blockIdx.x;
  const int m0 = mt * 128;
  const int nt = blockIdx.y;
  const int n0 = nt * 128;
  const int gp = blockIdx.z;
  const int g = gp / 9, p = gp - g * 9;
  const int pk = p / 3, pv = p - pk * 3;
  const int nm = (g == 1) ? 5 : 9;
  const int S = 2 * nm;

  const f32x4 zero = {0.f, 0.f, 0.f, 0.f};
  f32x4 acc[4][2];
#pragma unroll
  for (int i = 0; i < 4; ++i)
#pragma unroll
    for (int j = 0; j < 2; ++j) acc[i][j] = zero;

  auto STAGE = [&](int pbuf, int st) {
    const int u = st >> 1, kh = st & 1;
    const int s = (pk + SL_I[g][u]) * 7 + (pv + SL_J[g][u]);
    const unsigned short* srcA = Xb + ((size_t)((s * 32 + mt) * 2 + kh)) * 4096;
    const unsigned short* srcB = W5c + ((size_t)((gp * 9 + u) * 2 + nt)) * 8192 + kh * 4096;
    unsigned short* dA = smem + pbuf * 8192;
    unsigned short* dB = dA + 4096;
    GLDS16(srcA + t * 8, dA + t * 8);
    GLDS16(srcB + t * 8, dB + t * 8);
  };

  STAGE(0, 0);
  for (int st = 0; st < S; ++st) {
    if (st + 1 < S) { STAGE((st + 1) % 3, st + 1); VMW(2); } else { VMW(0); }
    SBAR(); SCB();
    const unsigned short* lA = smem + (st % 3) * 8192;
    const unsigned short* lB = lA + 4096;
    bf16x8 af[4], bfr[2];
#pragma unroll
    for (int f4 = 0; f4 < 4; ++f4)
      af[f4] = *reinterpret_cast<const bf16x8*>(lA + l4 * 1024 + (wm * 64 + f4 * 16 + l15) * 8);
#pragma unroll
    for (int f2 = 0; f2 < 2; ++f2)
      bfr[f2] = *reinterpret_cast<const bf16x8*>(lB + l4 * 1024 + (wn * 32 + f2 * 16 + l15) * 8);
#pragma unroll
    for (int i = 0; i < 4; ++i)
#pragma unroll
      for (int j = 0; j < 2; ++j)
        acc[i][j] = __builtin_amdgcn_mfma_f32_16x16x32_bf16(af[i], bfr[j], acc[i][j], 0, 0, 0);
  }
  __syncthreads();
  // epilogue: BN + mish -> bf16, LDS transpose -> dwordx4 stores (H pre-swizzled)
#pragma unroll
  for (int j = 0; j < 2; ++j) {
    const int col = wn * 32 + j * 16 + l15;
    const float a  = bn_a[gp * 256 + n0 + col];
    const float cc = bn_c[gp * 256 + n0 + col];
#pragma unroll
    for (int i = 0; i < 4; ++i) {
      const int r0 = wm * 64 + i * 16 + l4 * 4;
#pragma unroll
      for (int e = 0; e < 4; ++e) {
        const int r = r0 + e;
        float z = acc[i][j][e] * a + cc;
        smem[r * 128 + (col ^ ((r & 7) << 3))] = f2b(mish_f(z));
      }
    }
  }
  __syncthreads();
  {
    unsigned short* Hg = H + (size_t)gp * 1048576;
#pragma unroll
    for (int it = 0; it < 4; ++it) {
      int idx = it * 512 + t;
      int row = idx >> 4, seg = idx & 15;
      int c8 = (seg * 8) ^ ((row & 7) << 3);
      uint4 v = *(const uint4*)(smem + row * 128 + c8);
      int colout = n0 + (seg >> 3) * 64 + (((seg & 7) ^ (row & 7)) << 3);
      *(uint4*)(Hg + (size_t)(m0 + row) * 256 + colout) = v;
    }
  }
}

// ---- fused stages 2+3 with counted-vmcnt 3-buffer pipeline (R14/R16-proven) ----
__global__ __launch_bounds__(512) void gemm23f_k(const unsigned short* __restrict__ Hb,
                                                 const unsigned short* __restrict__ W1c,
                                                 const unsigned short* __restrict__ W2c,
                                                 const float* __restrict__ b1, const float* __restrict__ b2,
                                                 unsigned short* __restrict__ Obuf) {
  extern __shared__ unsigned short smem[];
  unsigned short* stB = smem;
  unsigned short* stA = smem + 24576;
  unsigned short* h1  = smem + 24576;
  const int t = threadIdx.x;
  const int lane = t & 63;
  const int w = t >> 6;
  const int wm = w >> 2, wn = w & 3;
  const int l15 = lane & 15, l4 = lane >> 4;
  const int sw = l15 & 7;
  const int m0 = blockIdx.x * 64;
  const int gp = blockIdx.y;

  const f32x4 zero = {0.f, 0.f, 0.f, 0.f};
  f32x4 acc[2][4];
#pragma unroll
  for (int i = 0; i < 2; ++i)
#pragma unroll
    for (int j = 0; j < 4; ++j) acc[i][j] = zero;

  auto STAGE_A = [&](int pbuf, int kt64) {
    unsigned short* dA = stA + pbuf * 4096;
    GLDS16(Hb + (size_t)(gp * 4096 + m0 + (t >> 3)) * 256 + kt64 * 64 + (t & 7) * 8, dA + t * 8);
  };
  auto STAGE_B = [&](const unsigned short* Wc, int kt32, int pbuf) {
    unsigned short* dB = stB + pbuf * 8192;
    const unsigned short* src = Wc + ((size_t)(gp * 8 + kt32)) * 8192;
#pragma unroll
    for (int it = 0; it < 2; ++it) {
      int idx = it * 512 + t;
      GLDS16(src + idx * 8, dB + idx * 8);
    }
  };

  // ---- phase 1: h1 = mish(H x W1^T + b1), 8 steps of BK=32 ----
  STAGE_A(0, 0);
  STAGE_B(W1c, 0, 0);
#pragma unroll
  for (int kt = 0; kt < 8; ++kt) {
    if (kt < 7) STAGE_B(W1c, kt + 1, (kt + 1) % 3);
    if ((kt & 1) == 0 && kt < 6) STAGE_A((kt / 2 + 1) % 3, kt / 2 + 1);
    if (kt < 6) { VMW(3); } else if (kt == 6) { VMW(2); } else { VMW(0); }
    SBAR(); SCB();
    const unsigned short* lA = stA + ((kt >> 1) % 3) * 4096;
    const unsigned short* lB = stB + (kt % 3) * 8192;
    bf16x8 af[2], bfr[4];
#pragma unroll
    for (int f2 = 0; f2 < 2; ++f2)
      af[f2] = *reinterpret_cast<const bf16x8*>(lA + (wm * 32 + f2 * 16 + l15) * 64 + ((((kt & 1) * 4 + l4) ^ sw) << 3));
#pragma unroll
    for (int f4 = 0; f4 < 4; ++f4)
      bfr[f4] = *reinterpret_cast<const bf16x8*>(lB + l4 * 2048 + (wn * 64 + f4 * 16 + l15) * 8);
#pragma unroll
    for (int i = 0; i < 2; ++i)
#pragma unroll
      for (int j = 0; j < 4; ++j)
        acc[i][j] = __builtin_amdgcn_mfma_f32_16x16x32_bf16(af[i], bfr[j], acc[i][j], 0, 0, 0);
  }
  __syncthreads();
  STAGE_B(W2c, 0, 0);              // prefetch W2 step 0 under the h1 epilogue
#pragma unroll
  for (int j = 0; j < 4; ++j) {
    const int c = wn * 64 + j * 16 + l15;
    const float bi = b1[gp * 256 + c];
#pragma unroll
    for (int i = 0; i < 2; ++i) {
      const int r0 = wm * 32 + i * 16 + l4 * 4;
#pragma unroll
      for (int e = 0; e < 4; ++e) {
        const int r = r0 + e;
        h1[r * 256 + swoff(c, r)] = f2b(mish_f(acc[i][j][e] + bi));
      }
    }
  }
  __syncthreads();                 // publishes h1; drains W2 step-0 stage

  // ---- phase 2: o = h1 x W2^T + b2, 8 steps of BK=32, staged 3-buffer ----
#pragma unroll
  for (int i = 0; i < 2; ++i)
#pragma unroll
    for (int j = 0; j < 4; ++j) acc[i][j] = zero;
#pragma unroll
  for (int kt = 0; kt < 8; ++kt) {
    if (kt < 7) STAGE_B(W2c, kt + 1, (kt + 1) % 3);
    if (kt < 7) { VMW(2); } else { VMW(0); }
    SBAR(); SCB();
    const unsigned short* lB = stB + (kt % 3) * 8192;
    bf16x8 af[2], bfr[4];
#pragma unroll
    for (int f2 = 0; f2 < 2; ++f2) {
      const int row = wm * 32 + f2 * 16 + l15;
      af[f2] = *reinterpret_cast<const bf16x8*>(
          h1 + row * 256 + (kt >> 1) * 64 + ((((kt & 1) * 4 + l4) ^ sw) << 3));
    }
#pragma unroll
    for (int f4 = 0; f4 < 4; ++f4)
      bfr[f4] = *reinterpret_cast<const bf16x8*>(lB + l4 * 2048 + (wn * 64 + f4 * 16 + l15) * 8);
#pragma unroll
    for (int i = 0; i < 2; ++i)
#pragma unroll
      for (int j = 0; j < 4; ++j)
        acc[i][j] = __builtin_amdgcn_mfma_f32_16x16x32_bf16(af[i], bfr[j], acc[i][j], 0, 0, 0);
  }
  __syncthreads();
  unsigned short* tr = stB;
#pragma unroll
  for (int j = 0; j < 4; ++j) {
    const int c = wn * 64 + j * 16 + l15;
    const float bi = b2[gp * 256 + c];
#pragma unroll
    for (int i = 0; i < 2; ++i) {
      const int r0 = wm * 32 + i * 16 + l4 * 4;
#pragma unroll
      for (int e = 0; e < 4; ++e) {
        const int r = r0 + e;
        tr[r * 256 + swoff(c, r)] = f2b(acc[i][j][e] + bi);
      }
    }
  }
  __syncthreads();
  {
    unsigned short* Og = Obuf + (size_t)gp * 1048576;
#pragma unroll
    for (int it = 0; it < 4; ++it) {
      int idx = it * 512 + t;
      int row = idx >> 5, seg = idx & 31;
      int c8 = swoff(seg * 8, row);
      uint4 v = *(const uint4*)(tr + row * 256 + c8);
      *(uint4*)(Og + (size_t)(m0 + row) * 256 + seg * 8) = v;
    }
  }
}

// ---- final: copy = sum_{gp<9} o, jump = sum_{gp>=9} o, out = copy*jump ----
__global__ __launch_bounds__(256) void final_k(const unsigned short* __restrict__ O, float* __restrict__ out) {
  const size_t base = ((size_t)blockIdx.x * 256 + threadIdx.x) * 8;
  float cs[8], js[8];
#pragma unroll
  for (int e = 0; e < 8; ++e) { cs[e] = 0.f; js[e] = 0.f; }
#pragma unroll
  for (int gp = 0; gp < 27; ++gp) {
    uint4 v = *(const uint4*)(O + (size_t)gp * 1048576 + base);
    const unsigned short* pv = (const unsigned short*)&v;
    if (gp < 9) {
#pragma unroll
      for (int e = 0; e < 8; ++e) cs[e] += b2f(pv[e]);
    } else {
#pragma unroll
      for (int e = 0; e < 8; ++e) js[e] += b2f(pv[e]);
    }
  }
  float4 o0 = {cs[0] * js[0], cs[1] * js[1], cs[2] * js[2], cs[3] * js[3]};
  float4 o1 = {cs[4] * js[4], cs[5] * js[5], cs[6] * js[6], cs[7] * js[7]};
  *(float4*)(out + base) = o0;
  *(float4*)(out + base + 4) = o1;
}

extern "C" void kernel_launch(void* const* d_in, const int* in_sizes, int n_in,
                              void* d_out, int out_size, void* d_ws, size_t ws_size,
                              hipStream_t stream) {
  const float* X     = (const float*)d_in[0];
  const float* W5    = (const float*)d_in[1];
  const float* b5    = (const float*)d_in[2];
  const float* gamma = (const float*)d_in[3];
  const float* beta  = (const float*)d_in[4];
  const float* rmean = (const float*)d_in[5];
  const float* rvar  = (const float*)d_in[6];
  const float* W1    = (const float*)d_in[7];
  const float* b1    = (const float*)d_in[8];
  const float* W2    = (const float*)d_in[9];
  const float* b2    = (const float*)d_in[10];
  float* out = (float*)d_out;
  char* ws = (char*)d_ws;

  unsigned short* W5c  = (unsigned short*)(ws);              //  7,962,624
  unsigned short* W1c  = (unsigned short*)(ws + 7962624);    //  3,538,944
  unsigned short* W2c  = (unsigned short*)(ws + 11501568);   //  3,538,944
  float*          bn_a = (float*)(ws + 15040512);            //     27,648
  float*          bn_c = (float*)(ws + 15068160);            //     27,648
  unsigned short* Xb   = (unsigned short*)(ws + 15095808);   // 25,690,112
  unsigned short* Hbuf = (unsigned short*)(ws + 40785920);   // 56,623,104
  unsigned short* Obuf = (unsigned short*)(ws + 97409024);   // 56,623,104

  (void)hipFuncSetAttribute(reinterpret_cast<const void*>(gemm23f_k),
                            hipFuncAttributeMaxDynamicSharedMemorySize, 81920);

  prep_all_k<<<3131, 256, 0, stream>>>(X, W5, W1, W2, b5, gamma, beta, rmean, rvar,
                                       Xb, W5c, W1c, W2c, bn_a, bn_c);

  gemm1_k<<<dim3(32, 2, 27), 512, 0, stream>>>(Xb, W5c, bn_a, bn_c, Hbuf);
  gemm23f_k<<<dim3(64, 27), 512, 81920, stream>>>(Hbuf, W1c, W2c, b1, b2, Obuf);
  final_k<<<512, 256, 0, stream>>>(Obuf, out);
}

// Round 22
// 142.498 us; speedup vs baseline: 1.1903x; 1.1486x over previous
//
#include <hip/hip_runtime.h>

typedef __bf16 bf16x8 __attribute__((ext_vector_type(8)));
typedef float f32x4 __attribute__((ext_vector_type(4)));

// mask position tables
__constant__ int SL_I[3][9] = {{1,1,1,2,2,2,3,3,3},{0,0,2,4,4,0,0,0,0},{0,0,1,1,2,3,3,4,4}};
__constant__ int SL_J[3][9] = {{1,2,3,1,2,3,1,2,3},{0,4,2,0,4,0,0,0,0},{1,3,0,4,2,0,4,1,3}};
__constant__ int SL_S[3][9] = {{6,7,8,11,12,13,16,17,18},{0,4,12,20,24,0,0,0,0},{1,3,5,9,12,15,19,21,23}};

#define GLDS16(gsrc, ldst)                                                        \
  __builtin_amdgcn_global_load_lds(                                               \
      (const __attribute__((address_space(1))) unsigned int*)(gsrc),              \
      (__attribute__((address_space(3))) unsigned int*)(ldst), 16, 0, 0)

#define SBAR()  asm volatile("s_barrier" ::: "memory")
#define VMW(n)  asm volatile("s_waitcnt vmcnt(" #n ")" ::: "memory")
#define SCB()   __builtin_amdgcn_sched_barrier(0)

static __device__ __forceinline__ unsigned short f2b(float f) {
  return __builtin_bit_cast(unsigned short, (__bf16)f);
}
static __device__ __forceinline__ float b2f(unsigned short u) {
  unsigned int b = ((unsigned int)u) << 16;
  return __builtin_bit_cast(float, b);
}
// mish(x) = x*w/(w+2), w = u*(u+2), u = e^x
static __device__ __forceinline__ float mish_f(float x) {
  float u = __expf(x);
  float w = u * (u + 2.0f);
  float r = x * w * __builtin_amdgcn_rcpf(w + 2.0f);
  return (x > 20.0f) ? x : r;
}
// A-side swizzle within a 64-col chunk (involution)
static __device__ __forceinline__ int swoff(int c, int r) {
  return (c & ~63) | ((c & 63) ^ ((r & 7) << 3));
}

// ---- merged prep: [0,512) x | [512,2240) w5 (LDS-staged) | [2240,3104) w12 | [3104,3131) bn ----
__global__ __launch_bounds__(256) void prep_all_k(const float* __restrict__ X,
                                                  const float* __restrict__ W5,
                                                  const float* __restrict__ W1, const float* __restrict__ W2,
                                                  const float* __restrict__ b5, const float* __restrict__ gamma,
                                                  const float* __restrict__ beta, const float* __restrict__ rmean,
                                                  const float* __restrict__ rvar,
                                                  unsigned short* __restrict__ Xb,
                                                  unsigned short* __restrict__ W5c,
                                                  unsigned short* __restrict__ W1c, unsigned short* __restrict__ W2c,
                                                  float* __restrict__ bn_a, float* __restrict__ bn_c) {
  __shared__ char shmem[50176];   // max(64*392*2, 6400*4)
  const int bid = blockIdx.x;
  const int t = threadIdx.x;
  if (bid < 512) {
    // ---- prep_x: block = (b-chunk of 64, oc). Fully coalesced loads AND stores. ----
    // tile[m][s][k] bf16; loads: 392 contiguous floats per X row; stores: 64 lanes
    // cover 64 consecutive m for one (s,oc) -> 1 KB contiguous, 16 full lines/instr.
    unsigned short* tile = (unsigned short*)shmem;   // 64*392 shorts = 50,176 B
    const int chunk = bid & 63;
    const int oc = bid >> 6;
    const int b0 = chunk * 64;
    const int c0 = oc * 8;
    for (int idx = t; idx < 25088; idx += 256) {
      const int i = idx / 392;
      const int r = idx - i * 392;       // r = k*49 + s
      const int k = r / 49;
      const int s = r - k * 49;
      tile[i * 392 + s * 8 + k] = f2b(X[(size_t)(b0 + i) * 3136 + c0 * 49 + r]);
    }
    __syncthreads();
    const int m = t & 63, w = t >> 6;
    const int mt = chunk >> 1, mof = (chunk & 1) * 64;
    for (int s = w; s < 49; s += 4) {
      uint4 v = *(const uint4*)(tile + m * 392 + s * 8);
      *(uint4*)(Xb + ((size_t)((s * 32 + mt) * 8 + oc)) * 1024 + (mof + m) * 8) = v;
    }
  } else if (bid < 512 + 1728) {
    // ---- prep_w5 (LDS-staged): block = (gp, nt, 4-row chunk) ----
    float* rows = (float*)shmem;           // 4 x 1600 f32 = 25600 B
    const int id = bid - 512;
    const int chunk = id & 31;
    const int nt = (id >> 5) & 1;
    const int gp = id >> 6;
    const int g = gp / 9;
    const int nm = (g == 1) ? 5 : 9;
    const int n0 = chunk * 4;
    const float* src = W5 + ((size_t)(gp * 256 + nt * 128 + n0)) * 1600;
    for (int i = t; i < 6400; i += 256) rows[i] = src[i];
    __syncthreads();
    for (int i = t; i < 576; i += 256) {   // u(9) x q(8) x k4(2) x n(4)
      const int n  = i & 3;
      const int k4 = (i >> 2) & 1;
      const int q  = (i >> 3) & 7;
      const int u  = i >> 6;
      if (u >= nm) continue;
      const int s = SL_S[g][u];
      const float* rp = rows + n * 1600 + s;
      const int c0 = q * 8 + k4 * 4;
      ushort4 v = {f2b(rp[(c0 + 0) * 25]), f2b(rp[(c0 + 1) * 25]),
                   f2b(rp[(c0 + 2) * 25]), f2b(rp[(c0 + 3) * 25])};
      *(ushort4*)(W5c + ((size_t)((gp * 9 + u) * 2 + nt)) * 8192 + q * 1024 + (n0 + n) * 8 + k4 * 4) = v;
    }
  } else if (bid < 512 + 1728 + 864) {
    // ---- prep_w12: W1/W2 -> fragment-major [gp][kt8][q4][n256][k8] ----
    int tid = (bid - 512 - 1728) * 256 + t;   // 221,184
    if (tid >= 221184) return;
    int n  = tid & 255;
    int q  = (tid >> 8) & 3;
    int kt = (tid >> 10) & 7;
    int gp = tid >> 13;
    size_t src = (size_t)(gp * 256 + n) * 256 + kt * 32 + q * 8;
    float4 a0 = *(const float4*)(W1 + src);
    float4 a1 = *(const float4*)(W1 + src + 4);
    float4 b0 = *(const float4*)(W2 + src);
    float4 b1 = *(const float4*)(W2 + src + 4);
    ushort4 ua0 = {f2b(a0.x), f2b(a0.y), f2b(a0.z), f2b(a0.w)};
    ushort4 ua1 = {f2b(a1.x), f2b(a1.y), f2b(a1.z), f2b(a1.w)};
    ushort4 ub0 = {f2b(b0.x), f2b(b0.y), f2b(b0.z), f2b(b0.w)};
    ushort4 ub1 = {f2b(b1.x), f2b(b1.y), f2b(b1.z), f2b(b1.w)};
    *(ushort4*)(W1c + (size_t)tid * 8) = ua0;
    *(ushort4*)(W1c + (size_t)tid * 8 + 4) = ua1;
    *(ushort4*)(W2c + (size_t)tid * 8) = ub0;
    *(ushort4*)(W2c + (size_t)tid * 8 + 4) = ub1;
  } else {
    // ---- prep_bn ----
    int i = (bid - 512 - 1728 - 864) * 256 + t;
    if (i < 27 * 256) {
      float a = gamma[i] * rsqrtf(rvar[i] + 1e-5f);
      bn_a[i] = a;
      bn_c[i] = (b5[i] - rmean[i]) * a + beta[i];
    }
  }
}

// ---- stage 1: z = Xb x W5c^T, BN + mish -> H bf16 (R16-proven 3-buffer pipeline) ----
__global__ __launch_bounds__(512) void gemm1_k(const unsigned short* __restrict__ Xb,
                                               const unsigned short* __restrict__ W5c,
                                               const float* __restrict__ bn_a, const float* __restrict__ bn_c,
                                               unsigned short* __restrict__ H) {
  __shared__ unsigned short smem[24576];   // 3 x (dA 4096 + dB 4096 shorts) = 48 KB
  const int t = threadIdx.x;
  const int lane = t & 63;
  const int w = t >> 6;
  const int wm = w >> 2, wn = w & 3;
  const int l15 = lane & 15, l4 = lane >> 4;
  const int mt = blockIdx.x;
  const int m0 = mt * 128;
  const int nt = blockIdx.y;
  const int n0 = nt * 128;
  const int gp = blockIdx.z;
  const int g = gp / 9, p = gp - g * 9;
  const int pk = p / 3, pv = p - pk * 3;
  const int nm = (g == 1) ? 5 : 9;
  const int S = 2 * nm;

  const f32x4 zero = {0.f, 0.f, 0.f, 0.f};
  f32x4 acc[4][2];
#pragma unroll
  for (int i = 0; i < 4; ++i)
#pragma unroll
    for (int j = 0; j < 2; ++j) acc[i][j] = zero;

  auto STAGE = [&](int pbuf, int st) {
    const int u = st >> 1, kh = st & 1;
    const int s = (pk + SL_I[g][u]) * 7 + (pv + SL_J[g][u]);
    const unsigned short* srcA = Xb + ((size_t)((s * 32 + mt) * 2 + kh)) * 4096;
    const unsigned short* srcB = W5c + ((size_t)((gp * 9 + u) * 2 + nt)) * 8192 + kh * 4096;
    unsigned short* dA = smem + pbuf * 8192;
    unsigned short* dB = dA + 4096;
    GLDS16(srcA + t * 8, dA + t * 8);
    GLDS16(srcB + t * 8, dB + t * 8);
  };

  STAGE(0, 0);
  for (int st = 0; st < S; ++st) {
    if (st + 1 < S) { STAGE((st + 1) % 3, st + 1); VMW(2); } else { VMW(0); }
    SBAR(); SCB();
    const unsigned short* lA = smem + (st % 3) * 8192;
    const unsigned short* lB = lA + 4096;
    bf16x8 af[4], bfr[2];
#pragma unroll
    for (int f4 = 0; f4 < 4; ++f4)
      af[f4] = *reinterpret_cast<const bf16x8*>(lA + l4 * 1024 + (wm * 64 + f4 * 16 + l15) * 8);
#pragma unroll
    for (int f2 = 0; f2 < 2; ++f2)
      bfr[f2] = *reinterpret_cast<const bf16x8*>(lB + l4 * 1024 + (wn * 32 + f2 * 16 + l15) * 8);
#pragma unroll
    for (int i = 0; i < 4; ++i)
#pragma unroll
      for (int j = 0; j < 2; ++j)
        acc[i][j] = __builtin_amdgcn_mfma_f32_16x16x32_bf16(af[i], bfr[j], acc[i][j], 0, 0, 0);
  }
  __syncthreads();
  // epilogue: BN + mish -> bf16, LDS transpose -> dwordx4 stores (H pre-swizzled)
#pragma unroll
  for (int j = 0; j < 2; ++j) {
    const int col = wn * 32 + j * 16 + l15;
    const float a  = bn_a[gp * 256 + n0 + col];
    const float cc = bn_c[gp * 256 + n0 + col];
#pragma unroll
    for (int i = 0; i < 4; ++i) {
      const int r0 = wm * 64 + i * 16 + l4 * 4;
#pragma unroll
      for (int e = 0; e < 4; ++e) {
        const int r = r0 + e;
        float z = acc[i][j][e] * a + cc;
        smem[r * 128 + (col ^ ((r & 7) << 3))] = f2b(mish_f(z));
      }
    }
  }
  __syncthreads();
  {
    unsigned short* Hg = H + (size_t)gp * 1048576;
#pragma unroll
    for (int it = 0; it < 4; ++it) {
      int idx = it * 512 + t;
      int row = idx >> 4, seg = idx & 15;
      int c8 = (seg * 8) ^ ((row & 7) << 3);
      uint4 v = *(const uint4*)(smem + row * 128 + c8);
      int colout = n0 + (seg >> 3) * 64 + (((seg & 7) ^ (row & 7)) << 3);
      *(uint4*)(Hg + (size_t)(m0 + row) * 256 + colout) = v;
    }
  }
}

// ---- fused stages 2+3 with counted-vmcnt 3-buffer pipeline (R14/R16-proven) ----
__global__ __launch_bounds__(512) void gemm23f_k(const unsigned short* __restrict__ Hb,
                                                 const unsigned short* __restrict__ W1c,
                                                 const unsigned short* __restrict__ W2c,
                                                 const float* __restrict__ b1, const float* __restrict__ b2,
                                                 unsigned short* __restrict__ Obuf) {
  extern __shared__ unsigned short smem[];
  unsigned short* stB = smem;
  unsigned short* stA = smem + 24576;
  unsigned short* h1  = smem + 24576;
  const int t = threadIdx.x;
  const int lane = t & 63;
  const int w = t >> 6;
  const int wm = w >> 2, wn = w & 3;
  const int l15 = lane & 15, l4 = lane >> 4;
  const int sw = l15 & 7;
  const int m0 = blockIdx.x * 64;
  const int gp = blockIdx.y;

  const f32x4 zero = {0.f, 0.f, 0.f, 0.f};
  f32x4 acc[2][4];
#pragma unroll
  for (int i = 0; i < 2; ++i)
#pragma unroll
    for (int j = 0; j < 4; ++j) acc[i][j] = zero;

  auto STAGE_A = [&](int pbuf, int kt64) {
    unsigned short* dA = stA + pbuf * 4096;
    GLDS16(Hb + (size_t)(gp * 4096 + m0 + (t >> 3)) * 256 + kt64 * 64 + (t & 7) * 8, dA + t * 8);
  };
  auto STAGE_B = [&](const unsigned short* Wc, int kt32, int pbuf) {
    unsigned short* dB = stB + pbuf * 8192;
    const unsigned short* src = Wc + ((size_t)(gp * 8 + kt32)) * 8192;
#pragma unroll
    for (int it = 0; it < 2; ++it) {
      int idx = it * 512 + t;
      GLDS16(src + idx * 8, dB + idx * 8);
    }
  };

  // ---- phase 1: h1 = mish(H x W1^T + b1), 8 steps of BK=32 ----
  STAGE_A(0, 0);
  STAGE_B(W1c, 0, 0);
#pragma unroll
  for (int kt = 0; kt < 8; ++kt) {
    if (kt < 7) STAGE_B(W1c, kt + 1, (kt + 1) % 3);
    if ((kt & 1) == 0 && kt < 6) STAGE_A((kt / 2 + 1) % 3, kt / 2 + 1);
    if (kt < 6) { VMW(3); } else if (kt == 6) { VMW(2); } else { VMW(0); }
    SBAR(); SCB();
    const unsigned short* lA = stA + ((kt >> 1) % 3) * 4096;
    const unsigned short* lB = stB + (kt % 3) * 8192;
    bf16x8 af[2], bfr[4];
#pragma unroll
    for (int f2 = 0; f2 < 2; ++f2)
      af[f2] = *reinterpret_cast<const bf16x8*>(lA + (wm * 32 + f2 * 16 + l15) * 64 + ((((kt & 1) * 4 + l4) ^ sw) << 3));
#pragma unroll
    for (int f4 = 0; f4 < 4; ++f4)
      bfr[f4] = *reinterpret_cast<const bf16x8*>(lB + l4 * 2048 + (wn * 64 + f4 * 16 + l15) * 8);
#pragma unroll
    for (int i = 0; i < 2; ++i)
#pragma unroll
      for (int j = 0; j < 4; ++j)
        acc[i][j] = __builtin_amdgcn_mfma_f32_16x16x32_bf16(af[i], bfr[j], acc[i][j], 0, 0, 0);
  }
  __syncthreads();
  STAGE_B(W2c, 0, 0);              // prefetch W2 step 0 under the h1 epilogue
#pragma unroll
  for (int j = 0; j < 4; ++j) {
    const int c = wn * 64 + j * 16 + l15;
    const float bi = b1[gp * 256 + c];
#pragma unroll
    for (int i = 0; i < 2; ++i) {
      const int r0 = wm * 32 + i * 16 + l4 * 4;
#pragma unroll
      for (int e = 0; e < 4; ++e) {
        const int r = r0 + e;
        h1[r * 256 + swoff(c, r)] = f2b(mish_f(acc[i][j][e] + bi));
      }
    }
  }
  __syncthreads();                 // publishes h1; drains W2 step-0 stage

  // ---- phase 2: o = h1 x W2^T + b2, 8 steps of BK=32, staged 3-buffer ----
#pragma unroll
  for (int i = 0; i < 2; ++i)
#pragma unroll
    for (int j = 0; j < 4; ++j) acc[i][j] = zero;
#pragma unroll
  for (int kt = 0; kt < 8; ++kt) {
    if (kt < 7) STAGE_B(W2c, kt + 1, (kt + 1) % 3);
    if (kt < 7) { VMW(2); } else { VMW(0); }
    SBAR(); SCB();
    const unsigned short* lB = stB + (kt % 3) * 8192;
    bf16x8 af[2], bfr[4];
#pragma unroll
    for (int f2 = 0; f2 < 2; ++f2) {
      const int row = wm * 32 + f2 * 16 + l15;
      af[f2] = *reinterpret_cast<const bf16x8*>(
          h1 + row * 256 + (kt >> 1) * 64 + ((((kt & 1) * 4 + l4) ^ sw) << 3));
    }
#pragma unroll
    for (int f4 = 0; f4 < 4; ++f4)
      bfr[f4] = *reinterpret_cast<const bf16x8*>(lB + l4 * 2048 + (wn * 64 + f4 * 16 + l15) * 8);
#pragma unroll
    for (int i = 0; i < 2; ++i)
#pragma unroll
      for (int j = 0; j < 4; ++j)
        acc[i][j] = __builtin_amdgcn_mfma_f32_16x16x32_bf16(af[i], bfr[j], acc[i][j], 0, 0, 0);
  }
  __syncthreads();
  unsigned short* tr = stB;
#pragma unroll
  for (int j = 0; j < 4; ++j) {
    const int c = wn * 64 + j * 16 + l15;
    const float bi = b2[gp * 256 + c];
#pragma unroll
    for (int i = 0; i < 2; ++i) {
      const int r0 = wm * 32 + i * 16 + l4 * 4;
#pragma unroll
      for (int e = 0; e < 4; ++e) {
        const int r = r0 + e;
        tr[r * 256 + swoff(c, r)] = f2b(acc[i][j][e] + bi);
      }
    }
  }
  __syncthreads();
  {
    unsigned short* Og = Obuf + (size_t)gp * 1048576;
#pragma unroll
    for (int it = 0; it < 4; ++it) {
      int idx = it * 512 + t;
      int row = idx >> 5, seg = idx & 31;
      int c8 = swoff(seg * 8, row);
      uint4 v = *(const uint4*)(tr + row * 256 + c8);
      *(uint4*)(Og + (size_t)(m0 + row) * 256 + seg * 8) = v;
    }
  }
}

// ---- final: copy = sum_{gp<9} o, jump = sum_{gp>=9} o, out = copy*jump ----
__global__ __launch_bounds__(256) void final_k(const unsigned short* __restrict__ O, float* __restrict__ out) {
  const size_t base = ((size_t)blockIdx.x * 256 + threadIdx.x) * 8;
  float cs[8], js[8];
#pragma unroll
  for (int e = 0; e < 8; ++e) { cs[e] = 0.f; js[e] = 0.f; }
#pragma unroll
  for (int gp = 0; gp < 27; ++gp) {
    uint4 v = *(const uint4*)(O + (size_t)gp * 1048576 + base);
    const unsigned short* pv = (const unsigned short*)&v;
    if (gp < 9) {
#pragma unroll
      for (int e = 0; e < 8; ++e) cs[e] += b2f(pv[e]);
    } else {
#pragma unroll
      for (int e = 0; e < 8; ++e) js[e] += b2f(pv[e]);
    }
  }
  float4 o0 = {cs[0] * js[0], cs[1] * js[1], cs[2] * js[2], cs[3] * js[3]};
  float4 o1 = {cs[4] * js[4], cs[5] * js[5], cs[6] * js[6], cs[7] * js[7]};
  *(float4*)(out + base) = o0;
  *(float4*)(out + base + 4) = o1;
}

extern "C" void kernel_launch(void* const* d_in, const int* in_sizes, int n_in,
                              void* d_out, int out_size, void* d_ws, size_t ws_size,
                              hipStream_t stream) {
  const float* X     = (const float*)d_in[0];
  const float* W5    = (const float*)d_in[1];
  const float* b5    = (const float*)d_in[2];
  const float* gamma = (const float*)d_in[3];
  const float* beta  = (const float*)d_in[4];
  const float* rmean = (const float*)d_in[5];
  const float* rvar  = (const float*)d_in[6];
  const float* W1    = (const float*)d_in[7];
  const float* b1    = (const float*)d_in[8];
  const float* W2    = (const float*)d_in[9];
  const float* b2    = (const float*)d_in[10];
  float* out = (float*)d_out;
  char* ws = (char*)d_ws;

  unsigned short* W5c  = (unsigned short*)(ws);              //  7,962,624
  unsigned short* W1c  = (unsigned short*)(ws + 7962624);    //  3,538,944
  unsigned short* W2c  = (unsigned short*)(ws + 11501568);   //  3,538,944
  float*          bn_a = (float*)(ws + 15040512);            //     27,648
  float*          bn_c = (float*)(ws + 15068160);            //     27,648
  unsigned short* Xb   = (unsigned short*)(ws + 15095808);   // 25,690,112
  unsigned short* Hbuf = (unsigned short*)(ws + 40785920);   // 56,623,104
  unsigned short* Obuf = (unsigned short*)(ws + 97409024);   // 56,623,104

  (void)hipFuncSetAttribute(reinterpret_cast<const void*>(gemm23f_k),
                            hipFuncAttributeMaxDynamicSharedMemorySize, 81920);

  prep_all_k<<<3131, 256, 0, stream>>>(X, W5, W1, W2, b5, gamma, beta, rmean, rvar,
                                       Xb, W5c, W1c, W2c, bn_a, bn_c);

  gemm1_k<<<dim3(32, 2, 27), 512, 0, stream>>>(Xb, W5c, bn_a, bn_c, Hbuf);
  gemm23f_k<<<dim3(64, 27), 512, 81920, stream>>>(Hbuf, W1c, W2c, b1, b2, Obuf);
  final_k<<<512, 256, 0, stream>>>(Obuf, out);
}

// Round 23
// 136.938 us; speedup vs baseline: 1.2386x; 1.0406x over previous
//
#include <hip/hip_runtime.h>

typedef __bf16 bf16x8 __attribute__((ext_vector_type(8)));
typedef float f32x4 __attribute__((ext_vector_type(4)));

// mask position tables
__constant__ int SL_I[3][9] = {{1,1,1,2,2,2,3,3,3},{0,0,2,4,4,0,0,0,0},{0,0,1,1,2,3,3,4,4}};
__constant__ int SL_J[3][9] = {{1,2,3,1,2,3,1,2,3},{0,4,2,0,4,0,0,0,0},{1,3,0,4,2,0,4,1,3}};
__constant__ int SL_S[3][9] = {{6,7,8,11,12,13,16,17,18},{0,4,12,20,24,0,0,0,0},{1,3,5,9,12,15,19,21,23}};

#define GLDS16(gsrc, ldst)                                                        \
  __builtin_amdgcn_global_load_lds(                                               \
      (const __attribute__((address_space(1))) unsigned int*)(gsrc),              \
      (__attribute__((address_space(3))) unsigned int*)(ldst), 16, 0, 0)

#define SBAR()  asm volatile("s_barrier" ::: "memory")
#define VMW(n)  asm volatile("s_waitcnt vmcnt(" #n ")" ::: "memory")
#define SCB()   __builtin_amdgcn_sched_barrier(0)

static __device__ __forceinline__ unsigned short f2b(float f) {
  return __builtin_bit_cast(unsigned short, (__bf16)f);
}
static __device__ __forceinline__ float b2f(unsigned short u) {
  unsigned int b = ((unsigned int)u) << 16;
  return __builtin_bit_cast(float, b);
}
// mish(x) = x*w/(w+2), w = u*(u+2), u = e^x
static __device__ __forceinline__ float mish_f(float x) {
  float u = __expf(x);
  float w = u * (u + 2.0f);
  float r = x * w * __builtin_amdgcn_rcpf(w + 2.0f);
  return (x > 20.0f) ? x : r;
}
// A-side swizzle within a 64-col chunk (involution)
static __device__ __forceinline__ int swoff(int c, int r) {
  return (c & ~63) | ((c & 63) ^ ((r & 7) << 3));
}

// ---- merged prep: [0,1024) x | [1024,2752) w5 (LDS-staged) | [2752,3616) w12 | [3616,3643) bn ----
__global__ __launch_bounds__(256) void prep_all_k(const float* __restrict__ X,
                                                  const float* __restrict__ W5,
                                                  const float* __restrict__ W1, const float* __restrict__ W2,
                                                  const float* __restrict__ b5, const float* __restrict__ gamma,
                                                  const float* __restrict__ beta, const float* __restrict__ rmean,
                                                  const float* __restrict__ rvar,
                                                  unsigned short* __restrict__ Xb,
                                                  unsigned short* __restrict__ W5c,
                                                  unsigned short* __restrict__ W1c, unsigned short* __restrict__ W2c,
                                                  float* __restrict__ bn_a, float* __restrict__ bn_c) {
  __shared__ char shmem[25600];   // max(32*392*2=25088, 6400*4=25600); ~6 blocks/CU
  const int bid = blockIdx.x;
  const int t = threadIdx.x;
  if (bid < 1024) {
    // ---- prep_x: block = (b-chunk of 32, oc). Coalesced loads AND stores, 6 blk/CU. ----
    unsigned short* tile = (unsigned short*)shmem;   // 32*392 shorts = 25,088 B
    const int chunk = bid & 127;       // 128 chunks of 32 rows
    const int oc = bid >> 7;           // 8
    const int b0 = chunk * 32;
    const int c0 = oc * 8;
    for (int idx = t; idx < 12544; idx += 256) {
      const int i = idx / 392;
      const int r = idx - i * 392;     // r = k*49 + s
      const int k = r / 49;
      const int s = r - k * 49;
      tile[i * 392 + s * 8 + k] = f2b(X[(size_t)(b0 + i) * 3136 + c0 * 49 + r]);
    }
    __syncthreads();
    const int m = t & 31, w = t >> 5;  // 8 groups of 32 lanes
    const int mt = chunk >> 2, mof = (chunk & 3) * 32;
    for (int s = w; s < 49; s += 8) {
      uint4 v = *(const uint4*)(tile + m * 392 + s * 8);
      *(uint4*)(Xb + ((size_t)((s * 32 + mt) * 8 + oc)) * 1024 + (mof + m) * 8) = v;
    }
  } else if (bid < 1024 + 1728) {
    // ---- prep_w5 (LDS-staged): block = (gp, nt, 4-row chunk) ----
    float* rows = (float*)shmem;           // 4 x 1600 f32 = 25600 B
    const int id = bid - 1024;
    const int chunk = id & 31;
    const int nt = (id >> 5) & 1;
    const int gp = id >> 6;
    const int g = gp / 9;
    const int nm = (g == 1) ? 5 : 9;
    const int n0 = chunk * 4;
    const float* src = W5 + ((size_t)(gp * 256 + nt * 128 + n0)) * 1600;
    for (int i = t; i < 6400; i += 256) rows[i] = src[i];
    __syncthreads();
    for (int i = t; i < 576; i += 256) {   // u(9) x q(8) x k4(2) x n(4)
      const int n  = i & 3;
      const int k4 = (i >> 2) & 1;
      const int q  = (i >> 3) & 7;
      const int u  = i >> 6;
      if (u >= nm) continue;
      const int s = SL_S[g][u];
      const float* rp = rows + n * 1600 + s;
      const int c0 = q * 8 + k4 * 4;
      ushort4 v = {f2b(rp[(c0 + 0) * 25]), f2b(rp[(c0 + 1) * 25]),
                   f2b(rp[(c0 + 2) * 25]), f2b(rp[(c0 + 3) * 25])};
      *(ushort4*)(W5c + ((size_t)((gp * 9 + u) * 2 + nt)) * 8192 + q * 1024 + (n0 + n) * 8 + k4 * 4) = v;
    }
  } else if (bid < 1024 + 1728 + 864) {
    // ---- prep_w12: W1/W2 -> fragment-major [gp][kt8][q4][n256][k8] ----
    int tid = (bid - 1024 - 1728) * 256 + t;   // 221,184
    if (tid >= 221184) return;
    int n  = tid & 255;
    int q  = (tid >> 8) & 3;
    int kt = (tid >> 10) & 7;
    int gp = tid >> 13;
    size_t src = (size_t)(gp * 256 + n) * 256 + kt * 32 + q * 8;
    float4 a0 = *(const float4*)(W1 + src);
    float4 a1 = *(const float4*)(W1 + src + 4);
    float4 b0 = *(const float4*)(W2 + src);
    float4 b1 = *(const float4*)(W2 + src + 4);
    ushort4 ua0 = {f2b(a0.x), f2b(a0.y), f2b(a0.z), f2b(a0.w)};
    ushort4 ua1 = {f2b(a1.x), f2b(a1.y), f2b(a1.z), f2b(a1.w)};
    ushort4 ub0 = {f2b(b0.x), f2b(b0.y), f2b(b0.z), f2b(b0.w)};
    ushort4 ub1 = {f2b(b1.x), f2b(b1.y), f2b(b1.z), f2b(b1.w)};
    *(ushort4*)(W1c + (size_t)tid * 8) = ua0;
    *(ushort4*)(W1c + (size_t)tid * 8 + 4) = ua1;
    *(ushort4*)(W2c + (size_t)tid * 8) = ub0;
    *(ushort4*)(W2c + (size_t)tid * 8 + 4) = ub1;
  } else {
    // ---- prep_bn ----
    int i = (bid - 1024 - 1728 - 864) * 256 + t;
    if (i < 27 * 256) {
      float a = gamma[i] * rsqrtf(rvar[i] + 1e-5f);
      bn_a[i] = a;
      bn_c[i] = (b5[i] - rmean[i]) * a + beta[i];
    }
  }
}

// ---- stage 1: z = Xb x W5c^T, BN + mish -> H bf16 (R16-proven 3-buffer pipeline) ----
__global__ __launch_bounds__(512) void gemm1_k(const unsigned short* __restrict__ Xb,
                                               const unsigned short* __restrict__ W5c,
                                               const float* __restrict__ bn_a, const float* __restrict__ bn_c,
                                               unsigned short* __restrict__ H) {
  __shared__ unsigned short smem[24576];   // 3 x (dA 4096 + dB 4096 shorts) = 48 KB
  const int t = threadIdx.x;
  const int lane = t & 63;
  const int w = t >> 6;
  const int wm = w >> 2, wn = w & 3;
  const int l15 = lane & 15, l4 = lane >> 4;
  const int mt = blockIdx.x;
  const int m0 = mt * 128;
  const int nt = blockIdx.y;
  const int n0 = nt * 128;
  const int gp = blockIdx.z;
  const int g = gp / 9, p = gp - g * 9;
  const int pk = p / 3, pv = p - pk * 3;
  const int nm = (g == 1) ? 5 : 9;
  const int S = 2 * nm;

  const f32x4 zero = {0.f, 0.f, 0.f, 0.f};
  f32x4 acc[4][2];
#pragma unroll
  for (int i = 0; i < 4; ++i)
#pragma unroll
    for (int j = 0; j < 2; ++j) acc[i][j] = zero;

  auto STAGE = [&](int pbuf, int st) {
    const int u = st >> 1, kh = st & 1;
    const int s = (pk + SL_I[g][u]) * 7 + (pv + SL_J[g][u]);
    const unsigned short* srcA = Xb + ((size_t)((s * 32 + mt) * 2 + kh)) * 4096;
    const unsigned short* srcB = W5c + ((size_t)((gp * 9 + u) * 2 + nt)) * 8192 + kh * 4096;
    unsigned short* dA = smem + pbuf * 8192;
    unsigned short* dB = dA + 4096;
    GLDS16(srcA + t * 8, dA + t * 8);
    GLDS16(srcB + t * 8, dB + t * 8);
  };

  STAGE(0, 0);
  for (int st = 0; st < S; ++st) {
    if (st + 1 < S) { STAGE((st + 1) % 3, st + 1); VMW(2); } else { VMW(0); }
    SBAR(); SCB();
    const unsigned short* lA = smem + (st % 3) * 8192;
    const unsigned short* lB = lA + 4096;
    bf16x8 af[4], bfr[2];
#pragma unroll
    for (int f4 = 0; f4 < 4; ++f4)
      af[f4] = *reinterpret_cast<const bf16x8*>(lA + l4 * 1024 + (wm * 64 + f4 * 16 + l15) * 8);
#pragma unroll
    for (int f2 = 0; f2 < 2; ++f2)
      bfr[f2] = *reinterpret_cast<const bf16x8*>(lB + l4 * 1024 + (wn * 32 + f2 * 16 + l15) * 8);
#pragma unroll
    for (int i = 0; i < 4; ++i)
#pragma unroll
      for (int j = 0; j < 2; ++j)
        acc[i][j] = __builtin_amdgcn_mfma_f32_16x16x32_bf16(af[i], bfr[j], acc[i][j], 0, 0, 0);
  }
  __syncthreads();
  // epilogue: BN + mish -> bf16, LDS transpose -> dwordx4 stores (H pre-swizzled)
#pragma unroll
  for (int j = 0; j < 2; ++j) {
    const int col = wn * 32 + j * 16 + l15;
    const float a  = bn_a[gp * 256 + n0 + col];
    const float cc = bn_c[gp * 256 + n0 + col];
#pragma unroll
    for (int i = 0; i < 4; ++i) {
      const int r0 = wm * 64 + i * 16 + l4 * 4;
#pragma unroll
      for (int e = 0; e < 4; ++e) {
        const int r = r0 + e;
        float z = acc[i][j][e] * a + cc;
        smem[r * 128 + (col ^ ((r & 7) << 3))] = f2b(mish_f(z));
      }
    }
  }
  __syncthreads();
  {
    unsigned short* Hg = H + (size_t)gp * 1048576;
#pragma unroll
    for (int it = 0; it < 4; ++it) {
      int idx = it * 512 + t;
      int row = idx >> 4, seg = idx & 15;
      int c8 = (seg * 8) ^ ((row & 7) << 3);
      uint4 v = *(const uint4*)(smem + row * 128 + c8);
      int colout = n0 + (seg >> 3) * 64 + (((seg & 7) ^ (row & 7)) << 3);
      *(uint4*)(Hg + (size_t)(m0 + row) * 256 + colout) = v;
    }
  }
}

// ---- fused stages 2+3 with counted-vmcnt 3-buffer pipeline (R14/R16-proven) ----
__global__ __launch_bounds__(512) void gemm23f_k(const unsigned short* __restrict__ Hb,
                                                 const unsigned short* __restrict__ W1c,
                                                 const unsigned short* __restrict__ W2c,
                                                 const float* __restrict__ b1, const float* __restrict__ b2,
                                                 unsigned short* __restrict__ Obuf) {
  extern __shared__ unsigned short smem[];
  unsigned short* stB = smem;
  unsigned short* stA = smem + 24576;
  unsigned short* h1  = smem + 24576;
  const int t = threadIdx.x;
  const int lane = t & 63;
  const int w = t >> 6;
  const int wm = w >> 2, wn = w & 3;
  const int l15 = lane & 15, l4 = lane >> 4;
  const int sw = l15 & 7;
  const int m0 = blockIdx.x * 64;
  const int gp = blockIdx.y;

  const f32x4 zero = {0.f, 0.f, 0.f, 0.f};
  f32x4 acc[2][4];
#pragma unroll
  for (int i = 0; i < 2; ++i)
#pragma unroll
    for (int j = 0; j < 4; ++j) acc[i][j] = zero;

  auto STAGE_A = [&](int pbuf, int kt64) {
    unsigned short* dA = stA + pbuf * 4096;
    GLDS16(Hb + (size_t)(gp * 4096 + m0 + (t >> 3)) * 256 + kt64 * 64 + (t & 7) * 8, dA + t * 8);
  };
  auto STAGE_B = [&](const unsigned short* Wc, int kt32, int pbuf) {
    unsigned short* dB = stB + pbuf * 8192;
    const unsigned short* src = Wc + ((size_t)(gp * 8 + kt32)) * 8192;
#pragma unroll
    for (int it = 0; it < 2; ++it) {
      int idx = it * 512 + t;
      GLDS16(src + idx * 8, dB + idx * 8);
    }
  };

  // ---- phase 1: h1 = mish(H x W1^T + b1), 8 steps of BK=32 ----
  STAGE_A(0, 0);
  STAGE_B(W1c, 0, 0);
#pragma unroll
  for (int kt = 0; kt < 8; ++kt) {
    if (kt < 7) STAGE_B(W1c, kt + 1, (kt + 1) % 3);
    if ((kt & 1) == 0 && kt < 6) STAGE_A((kt / 2 + 1) % 3, kt / 2 + 1);
    if (kt < 6) { VMW(3); } else if (kt == 6) { VMW(2); } else { VMW(0); }
    SBAR(); SCB();
    const unsigned short* lA = stA + ((kt >> 1) % 3) * 4096;
    const unsigned short* lB = stB + (kt % 3) * 8192;
    bf16x8 af[2], bfr[4];
#pragma unroll
    for (int f2 = 0; f2 < 2; ++f2)
      af[f2] = *reinterpret_cast<const bf16x8*>(lA + (wm * 32 + f2 * 16 + l15) * 64 + ((((kt & 1) * 4 + l4) ^ sw) << 3));
#pragma unroll
    for (int f4 = 0; f4 < 4; ++f4)
      bfr[f4] = *reinterpret_cast<const bf16x8*>(lB + l4 * 2048 + (wn * 64 + f4 * 16 + l15) * 8);
#pragma unroll
    for (int i = 0; i < 2; ++i)
#pragma unroll
      for (int j = 0; j < 4; ++j)
        acc[i][j] = __builtin_amdgcn_mfma_f32_16x16x32_bf16(af[i], bfr[j], acc[i][j], 0, 0, 0);
  }
  __syncthreads();
  STAGE_B(W2c, 0, 0);              // prefetch W2 step 0 under the h1 epilogue
#pragma unroll
  for (int j = 0; j < 4; ++j) {
    const int c = wn * 64 + j * 16 + l15;
    const float bi = b1[gp * 256 + c];
#pragma unroll
    for (int i = 0; i < 2; ++i) {
      const int r0 = wm * 32 + i * 16 + l4 * 4;
#pragma unroll
      for (int e = 0; e < 4; ++e) {
        const int r = r0 + e;
        h1[r * 256 + swoff(c, r)] = f2b(mish_f(acc[i][j][e] + bi));
      }
    }
  }
  __syncthreads();                 // publishes h1; drains W2 step-0 stage

  // ---- phase 2: o = h1 x W2^T + b2, 8 steps of BK=32, staged 3-buffer ----
#pragma unroll
  for (int i = 0; i < 2; ++i)
#pragma unroll
    for (int j = 0; j < 4; ++j) acc[i][j] = zero;
#pragma unroll
  for (int kt = 0; kt < 8; ++kt) {
    if (kt < 7) STAGE_B(W2c, kt + 1, (kt + 1) % 3);
    if (kt < 7) { VMW(2); } else { VMW(0); }
    SBAR(); SCB();
    const unsigned short* lB = stB + (kt % 3) * 8192;
    bf16x8 af[2], bfr[4];
#pragma unroll
    for (int f2 = 0; f2 < 2; ++f2) {
      const int row = wm * 32 + f2 * 16 + l15;
      af[f2] = *reinterpret_cast<const bf16x8*>(
          h1 + row * 256 + (kt >> 1) * 64 + ((((kt & 1) * 4 + l4) ^ sw) << 3));
    }
#pragma unroll
    for (int f4 = 0; f4 < 4; ++f4)
      bfr[f4] = *reinterpret_cast<const bf16x8*>(lB + l4 * 2048 + (wn * 64 + f4 * 16 + l15) * 8);
#pragma unroll
    for (int i = 0; i < 2; ++i)
#pragma unroll
      for (int j = 0; j < 4; ++j)
        acc[i][j] = __builtin_amdgcn_mfma_f32_16x16x32_bf16(af[i], bfr[j], acc[i][j], 0, 0, 0);
  }
  __syncthreads();
  unsigned short* tr = stB;
#pragma unroll
  for (int j = 0; j < 4; ++j) {
    const int c = wn * 64 + j * 16 + l15;
    const float bi = b2[gp * 256 + c];
#pragma unroll
    for (int i = 0; i < 2; ++i) {
      const int r0 = wm * 32 + i * 16 + l4 * 4;
#pragma unroll
      for (int e = 0; e < 4; ++e) {
        const int r = r0 + e;
        tr[r * 256 + swoff(c, r)] = f2b(acc[i][j][e] + bi);
      }
    }
  }
  __syncthreads();
  {
    unsigned short* Og = Obuf + (size_t)gp * 1048576;
#pragma unroll
    for (int it = 0; it < 4; ++it) {
      int idx = it * 512 + t;
      int row = idx >> 5, seg = idx & 31;
      int c8 = swoff(seg * 8, row);
      uint4 v = *(const uint4*)(tr + row * 256 + c8);
      *(uint4*)(Og + (size_t)(m0 + row) * 256 + seg * 8) = v;
    }
  }
}

// ---- final: copy = sum_{gp<9} o, jump = sum_{gp>=9} o, out = copy*jump ----
__global__ __launch_bounds__(256) void final_k(const unsigned short* __restrict__ O, float* __restrict__ out) {
  const size_t base = ((size_t)blockIdx.x * 256 + threadIdx.x) * 8;
  float cs[8], js[8];
#pragma unroll
  for (int e = 0; e < 8; ++e) { cs[e] = 0.f; js[e] = 0.f; }
#pragma unroll
  for (int gp = 0; gp < 27; ++gp) {
    uint4 v = *(const uint4*)(O + (size_t)gp * 1048576 + base);
    const unsigned short* pv = (const unsigned short*)&v;
    if (gp < 9) {
#pragma unroll
      for (int e = 0; e < 8; ++e) cs[e] += b2f(pv[e]);
    } else {
#pragma unroll
      for (int e = 0; e < 8; ++e) js[e] += b2f(pv[e]);
    }
  }
  float4 o0 = {cs[0] * js[0], cs[1] * js[1], cs[2] * js[2], cs[3] * js[3]};
  float4 o1 = {cs[4] * js[4], cs[5] * js[5], cs[6] * js[6], cs[7] * js[7]};
  *(float4*)(out + base) = o0;
  *(float4*)(out + base + 4) = o1;
}

extern "C" void kernel_launch(void* const* d_in, const int* in_sizes, int n_in,
                              void* d_out, int out_size, void* d_ws, size_t ws_size,
                              hipStream_t stream) {
  const float* X     = (const float*)d_in[0];
  const float* W5    = (const float*)d_in[1];
  const float* b5    = (const float*)d_in[2];
  const float* gamma = (const float*)d_in[3];
  const float* beta  = (const float*)d_in[4];
  const float* rmean = (const float*)d_in[5];
  const float* rvar  = (const float*)d_in[6];
  const float* W1    = (const float*)d_in[7];
  const float* b1    = (const float*)d_in[8];
  const float* W2    = (const float*)d_in[9];
  const float* b2    = (const float*)d_in[10];
  float* out = (float*)d_out;
  char* ws = (char*)d_ws;

  unsigned short* W5c  = (unsigned short*)(ws);              //  7,962,624
  unsigned short* W1c  = (unsigned short*)(ws + 7962624);    //  3,538,944
  unsigned short* W2c  = (unsigned short*)(ws + 11501568);   //  3,538,944
  float*          bn_a = (float*)(ws + 15040512);            //     27,648
  float*          bn_c = (float*)(ws + 15068160);            //     27,648
  unsigned short* Xb   = (unsigned short*)(ws + 15095808);   // 25,690,112
  unsigned short* Hbuf = (unsigned short*)(ws + 40785920);   // 56,623,104
  unsigned short* Obuf = (unsigned short*)(ws + 97409024);   // 56,623,104

  (void)hipFuncSetAttribute(reinterpret_cast<const void*>(gemm23f_k),
                            hipFuncAttributeMaxDynamicSharedMemorySize, 81920);

  prep_all_k<<<3643, 256, 0, stream>>>(X, W5, W1, W2, b5, gamma, beta, rmean, rvar,
                                       Xb, W5c, W1c, W2c, bn_a, bn_c);

  gemm1_k<<<dim3(32, 2, 27), 512, 0, stream>>>(Xb, W5c, bn_a, bn_c, Hbuf);
  gemm23f_k<<<dim3(64, 27), 512, 81920, stream>>>(Hbuf, W1c, W2c, b1, b2, Obuf);
  final_k<<<512, 256, 0, stream>>>(Obuf, out);
}